// Round 5
// baseline (263.720 us; speedup 1.0000x reference)
//
#include <hip/hip_runtime.h>
#include <type_traits>

typedef unsigned short u16;
typedef __attribute__((ext_vector_type(8))) short short8;   // 8 bf16 (4 VGPRs) MFMA frag
typedef __attribute__((ext_vector_type(4))) float floatx4;  // MFMA acc

#define DEV __device__ __forceinline__

DEV float bf2f(u16 u) { return __uint_as_float(((unsigned)u) << 16); }
DEV u16 f2bf(float f) {                       // RNE fp32->bf16
  unsigned u = __float_as_uint(f);
  u += 0x7fffu + ((u >> 16) & 1u);
  return (u16)(u >> 16);
}
DEV void unpack8(uint4 v, float* f) {
  f[0] = __uint_as_float(v.x << 16); f[1] = __uint_as_float(v.x & 0xffff0000u);
  f[2] = __uint_as_float(v.y << 16); f[3] = __uint_as_float(v.y & 0xffff0000u);
  f[4] = __uint_as_float(v.z << 16); f[5] = __uint_as_float(v.z & 0xffff0000u);
  f[6] = __uint_as_float(v.w << 16); f[7] = __uint_as_float(v.w & 0xffff0000u);
}
DEV void async16(const void* g, void* lds) {  // 16B global->LDS DMA (lane*16 implicit)
  __builtin_amdgcn_global_load_lds((const __attribute__((address_space(1))) void*)g,
                                   (__attribute__((address_space(3))) void*)lds, 16, 0, 0);
}

// ---------------- fused prep: X fp32->bf16 convert (blocks 0..4095) +
//                  weight transpose-convert + bias3 pack (blocks 4096..8191) ----------------
__global__ __launch_bounds__(256)
void k_prep(const float* __restrict__ X, const float* __restrict__ Wq, const float* __restrict__ Wk,
            const float* __restrict__ Wv, const float* __restrict__ Wo,
            const float* __restrict__ bq, const float* __restrict__ bk, const float* __restrict__ bv,
            u16* __restrict__ Xb, u16* __restrict__ Wqkvt, u16* __restrict__ Wot,
            float* __restrict__ bias3) {
  if (blockIdx.x < 4096) {                  // ---- X convert ----
    size_t i = ((size_t)blockIdx.x * 256 + threadIdx.x) * 8;
    float4 a = *(const float4*)(X + i);
    float4 b = *(const float4*)(X + i + 4);
    union { u16 s[8]; uint4 v; } o;
    o.s[0]=f2bf(a.x); o.s[1]=f2bf(a.y); o.s[2]=f2bf(a.z); o.s[3]=f2bf(a.w);
    o.s[4]=f2bf(b.x); o.s[5]=f2bf(b.y); o.s[6]=f2bf(b.z); o.s[7]=f2bf(b.w);
    *(uint4*)(Xb + i) = o.v;
    return;
  }
  // ---- weight transpose-convert: rb = z*1024 + by*32 + bx ----
  const int rb = blockIdx.x - 4096;
  const int z = rb >> 10, bxx = rb & 31, byy = (rb >> 5) & 31;
  const float* src; u16* dst;
  switch (z) {
    case 0:  src = Wq; dst = Wqkvt;            break;
    case 1:  src = Wk; dst = Wqkvt + 1048576;  break;
    case 2:  src = Wv; dst = Wqkvt + 2097152;  break;
    default: src = Wo; dst = Wot;              break;
  }
  __shared__ float tile[32][33];
  int tx = threadIdx.x & 31, ty = threadIdx.x >> 5;  // 32 x 8
  int n0 = bxx * 32, k0 = byy * 32;
  #pragma unroll
  for (int i = 0; i < 32; i += 8) tile[ty + i][tx] = src[(size_t)(k0 + ty + i) * 1024 + n0 + tx];
  if (z == 3 && bxx == 0 && byy == 0) {
    for (int i = threadIdx.x; i < 3072; i += 256)
      bias3[i] = (i < 1024) ? bq[i] : (i < 2048 ? bk[i - 1024] : bv[i - 2048]);
  }
  __syncthreads();
  #pragma unroll
  for (int i = 0; i < 32; i += 8) dst[(size_t)(n0 + ty + i) * 1024 + k0 + tx] = f2bf(tile[tx][ty + i]);
}

// ---------------- bf16 MFMA GEMM: C[M,N] = A[M,K] * Bt[N,K]^T + bias ----------------
// m97 structure: 128x128 tile, BK=32, 4 waves each 64x64 (4x4 MFMA 16x16x32), global_load_lds w=16
template <typename OutT>
__global__ __launch_bounds__(256)
void k_gemm_bt(const u16* __restrict__ A, const u16* __restrict__ B,
               const float* __restrict__ bias, OutT* __restrict__ C,
               int M, int N, int K) {
  __shared__ __align__(16) u16 As[128 * 32];
  __shared__ __align__(16) u16 Bs[128 * 32];
  const int t = threadIdx.x;
  const int w = t >> 6, lane = t & 63;
  const int m0 = blockIdx.y << 7, n0 = blockIdx.x << 7;
  const int wr = (w >> 1) << 6, wc = (w & 1) << 6;

  floatx4 acc[4][4];
  #pragma unroll
  for (int i = 0; i < 4; ++i)
    #pragma unroll
    for (int j = 0; j < 4; ++j)
      #pragma unroll
      for (int k = 0; k < 4; ++k) acc[i][j][k] = 0.f;

  const int rowA0 = t >> 2, koff = (t & 3) << 3;      // round 0: idx = t
  const int rowA1 = (256 + t) >> 2;                   // round 1: idx = 256+t (same koff)
  const int lr = lane & 15, lko = (lane >> 4) << 3;

  for (int kt = 0; kt < K; kt += 32) {
    __syncthreads();
    async16(A + (size_t)(m0 + rowA0) * K + kt + koff, &As[(w << 6) * 8]);
    async16(B + (size_t)(n0 + rowA0) * K + kt + koff, &Bs[(w << 6) * 8]);
    async16(A + (size_t)(m0 + rowA1) * K + kt + koff, &As[(256 + (w << 6)) * 8]);
    async16(B + (size_t)(n0 + rowA1) * K + kt + koff, &Bs[(256 + (w << 6)) * 8]);
    __syncthreads();
    short8 af[4], bfr[4];
    #pragma unroll
    for (int i = 0; i < 4; ++i) af[i]  = *(const short8*)&As[(wr + (i << 4) + lr) * 32 + lko];
    #pragma unroll
    for (int j = 0; j < 4; ++j) bfr[j] = *(const short8*)&Bs[(wc + (j << 4) + lr) * 32 + lko];
    #pragma unroll
    for (int i = 0; i < 4; ++i)
      #pragma unroll
      for (int j = 0; j < 4; ++j)
        acc[i][j] = __builtin_amdgcn_mfma_f32_16x16x32_bf16(af[i], bfr[j], acc[i][j], 0, 0, 0);
  }
  // C/D layout: col = lane&15, row = (lane>>4)*4 + reg
  const int lq = (lane >> 4) << 2;
  #pragma unroll
  for (int j = 0; j < 4; ++j) {
    const int cn = n0 + wc + (j << 4) + lr;
    const float bv = bias[cn];
    #pragma unroll
    for (int i = 0; i < 4; ++i) {
      const int rm = m0 + wr + (i << 4) + lq;
      #pragma unroll
      for (int rr = 0; rr < 4; ++rr) {
        float v = acc[i][j][rr] + bv;
        if constexpr (std::is_same<OutT, u16>::value) C[(size_t)(rm + rr) * N + cn] = f2bf(v);
        else                                          C[(size_t)(rm + rr) * N + cn] = v;
      }
    }
  }
}

// ---------------- Gram partials via MFMA + qsum partials ----------------
// Per block (chunk, nh): Qt = Q^T slab (64 x, 256 a) in LDS; one b128 frag set serves as
// both A and B operand (Gram symmetry); wave w computes C tile-row i=w.
__global__ __launch_bounds__(256)
void k_gpart2(const u16* __restrict__ QKV, float* __restrict__ Gpart, float* __restrict__ qpart) {
  const int chunk = blockIdx.x;            // 0..7 (256 a each)
  const int nh = blockIdx.y;               // 0..63
  const int n = nh >> 4, h = nh & 15;
  const int t = threadIdx.x, w = t >> 6, lane = t & 63;
  const int lr = lane & 15, lko = (lane >> 4) << 3;

  __shared__ __align__(16) u16 Qt[64 * 264];   // x-major, a-stride-padded (33.8 KB)
  __shared__ float red[256];

  // transpose-in: thread t <-> a_local = t; reads its full 64-dim Q row (8x uint4, 128 B)
  const int a = chunk * 256 + t;
  const uint4* qp = (const uint4*)(QKV + (size_t)(n * 2048 + h * 128 + (a >> 4)) * 3072 + ((t & 15) << 6));
  union { u16 s[8]; uint4 v; } qv[8];
  #pragma unroll
  for (int j = 0; j < 8; ++j) qv[j].v = qp[j];
  #pragma unroll
  for (int j = 0; j < 8; ++j)
    #pragma unroll
    for (int e = 0; e < 8; ++e)
      Qt[(j * 8 + e) * 264 + t] = qv[j].s[e];   // writes: consecutive a per lane -> 2-way, free
  __syncthreads();

  // qsum partial: thread (x = t&63, c = t>>6) sums Qt[x][c*64 .. +63]
  {
    const int x = t & 63, c = t >> 6;
    const u16* base = &Qt[x * 264 + c * 64];
    float s = 0.f;
    #pragma unroll
    for (int k = 0; k < 8; ++k) {
      float f[8]; unpack8(*(const uint4*)(base + k * 8), f);
      #pragma unroll
      for (int e = 0; e < 8; ++e) s += f[e];
    }
    red[t] = s;
  }
  __syncthreads();
  if (t < 64)
    qpart[((size_t)nh * 8 + chunk) * 64 + t] = red[t] + red[t + 64] + red[t + 128] + red[t + 192];

  // Gram: K-loop over 256 a in 8 steps of 32; wave w owns C tile-row i=w
  floatx4 acc[4];
  #pragma unroll
  for (int j = 0; j < 4; ++j)
    #pragma unroll
    for (int k = 0; k < 4; ++k) acc[j][k] = 0.f;
  for (int ks = 0; ks < 8; ++ks) {
    short8 f[4];
    #pragma unroll
    for (int i = 0; i < 4; ++i) f[i] = *(const short8*)&Qt[((i << 4) + lr) * 264 + (ks << 5) + lko];
    #pragma unroll
    for (int j = 0; j < 4; ++j)
      acc[j] = __builtin_amdgcn_mfma_f32_16x16x32_bf16(f[w], f[j], acc[j], 0, 0, 0);
  }
  float* o = Gpart + ((size_t)nh * 8 + chunk) * 4096;
  const int quad = lane >> 4;
  #pragma unroll
  for (int j = 0; j < 4; ++j)
    #pragma unroll
    for (int r = 0; r < 4; ++r)
      o[((w << 4) + (quad << 2) + r) * 64 + (j << 4) + lr] = acc[j][r];
}

// ---------------- fused: G-reduce -> U = K*G (MFMA, LDS) -> Taylor denom/diag -> mid = diag*V ----
__global__ __launch_bounds__(256)
void k_kgd(const u16* __restrict__ QKV, const float* __restrict__ Gpart,
           const float* __restrict__ qpart, u16* __restrict__ mid) {
  const int chunk = blockIdx.x;            // 0..7 (256 a each)
  const int nh = blockIdx.y;               // 0..63
  const int n = nh >> 4, h = nh & 15;
  const int t = threadIdx.x, w = t >> 6, lane = t & 63;
  const int lr = lane & 15, lko = (lane >> 4) << 3;

  __shared__ u16 Gs[4096];                 // bf16 G_h, 64x64 (8 KB)
  __shared__ __align__(16) u16 Us[256 * 72];  // bf16 U rows, padded stride 72 (36.9 KB)
  __shared__ float qs[64];

  // --- stage 0: reduce Gpart (8 chunks) -> Gs bf16; load qs ---
  const float* gp0 = Gpart + (size_t)nh * 8 * 4096;
  #pragma unroll
  for (int i = 0; i < 16; ++i) {
    int e = (i << 8) + t;
    float s = 0.f;
    #pragma unroll
    for (int c = 0; c < 8; ++c) s += gp0[c * 4096 + e];
    Gs[e] = f2bf(s);
  }
  if (t < 64) {
    float s = 0.f;
    #pragma unroll
    for (int rc = 0; rc < 8; ++rc) s += qpart[((size_t)nh * 8 + rc) * 64 + t];
    qs[t] = s;
  }
  __syncthreads();

  // --- stage 1: U = K * G via MFMA (each wave: 64 a-rows x 64 cols) ---
  short8 af[4][2], bfr[4][2];
  #pragma unroll
  for (int i = 0; i < 4; ++i) {
    const int arow = chunk * 16 + (w << 2) + i;         // (a>>4) within head
    const u16* kp = QKV + (size_t)(n * 2048 + h * 128 + arow) * 3072 + 1024 + lr * 64;
    #pragma unroll
    for (int s = 0; s < 2; ++s) af[i][s] = *(const short8*)(kp + s * 32 + lko);
  }
  #pragma unroll
  for (int j = 0; j < 4; ++j)
    #pragma unroll
    for (int s = 0; s < 2; ++s)
      bfr[j][s] = *(const short8*)&Gs[((j << 4) + lr) * 64 + s * 32 + lko];
  floatx4 acc[4][4];
  #pragma unroll
  for (int i = 0; i < 4; ++i)
    #pragma unroll
    for (int j = 0; j < 4; ++j)
      #pragma unroll
      for (int k = 0; k < 4; ++k) acc[i][j][k] = 0.f;
  #pragma unroll
  for (int s = 0; s < 2; ++s)
    #pragma unroll
    for (int i = 0; i < 4; ++i)
      #pragma unroll
      for (int j = 0; j < 4; ++j)
        acc[i][j] = __builtin_amdgcn_mfma_f32_16x16x32_bf16(af[i][s], bfr[j][s], acc[i][j], 0, 0, 0);
  const int rq = (lane >> 4) << 2;
  #pragma unroll
  for (int i = 0; i < 4; ++i)
    #pragma unroll
    for (int j = 0; j < 4; ++j)
      #pragma unroll
      for (int r = 0; r < 4; ++r) {
        int a_local = (w << 6) + (i << 4) + rq + r;     // 0..255
        Us[a_local * 72 + (j << 4) + lr] = f2bf(acc[i][j][r]);
      }
  __syncthreads();

  // --- stage 2: per-thread a: Taylor denom + diag; mid = diag * V ---
  const int b = chunk * 256 + t;           // a within head
  const int R = n * 2048 + h * 128 + (b >> 4);
  const u16* row = QKV + (size_t)R * 3072 + ((b & 15) << 6);
  const uint4* qp = (const uint4*)row;
  const uint4* kp = (const uint4*)(row + 1024);
  const uint4* vp = (const uint4*)(row + 2048);
  const uint4* up = (const uint4*)&Us[t * 72];
  float sbb = 0.f, s1 = 0.f, quad = 0.f;
  #pragma unroll
  for (int xo = 0; xo < 8; ++xo) {
    float kx[8], qx[8], ux[8];
    unpack8(kp[xo], kx); unpack8(qp[xo], qx); unpack8(up[xo], ux);
    #pragma unroll
    for (int xi = 0; xi < 8; ++xi) {
      sbb  += qx[xi] * kx[xi];
      quad += ux[xi] * kx[xi];
      s1   += qs[xo * 8 + xi] * kx[xi];
    }
  }
  const float c1 = 0.0009765625f;  // 1/1024
  float denom = 2048.f + s1 * c1 + 0.5f * quad * c1 * c1;
  float d = expf(sbb * c1) / denom;
  u16* mp = mid + (size_t)R * 1024 + ((b & 15) << 6);
  #pragma unroll
  for (int xo = 0; xo < 8; ++xo) {
    float f[8]; unpack8(vp[xo], f);
    union { u16 s[8]; uint4 v; } o;
    #pragma unroll
    for (int k = 0; k < 8; ++k) o.s[k] = f2bf(f[k] * d);
    *(uint4*)(mp + xo * 8) = o.v;
  }
}

// ---------------- launch ----------------
extern "C" void kernel_launch(void* const* d_in, const int* in_sizes, int n_in,
                              void* d_out, int out_size, void* d_ws, size_t ws_size,
                              hipStream_t stream) {
  (void)in_sizes; (void)n_in; (void)out_size; (void)ws_size;
  const float* X  = (const float*)d_in[0];
  const float* Wq = (const float*)d_in[1];
  const float* bq = (const float*)d_in[2];
  const float* Wk = (const float*)d_in[3];
  const float* bk = (const float*)d_in[4];
  const float* Wv = (const float*)d_in[5];
  const float* bv = (const float*)d_in[6];
  const float* Wo = (const float*)d_in[7];
  const float* bo = (const float*)d_in[8];
  float* out = (float*)d_out;
  char* ws = (char*)d_ws;

  u16*   Xb    = (u16*)(ws + 0);                 // 16 MB (dead after QKV GEMM)
  u16*   mid   = (u16*)(ws + 0);                 // overlays Xb (written after Xb is dead)
  u16*   Wqkvt = (u16*)(ws + 16777216);          //  6 MB
  u16*   Wot   = (u16*)(ws + 23068672);          //  2 MB
  float* bias3 = (float*)(ws + 25165824);        // 12 KB
  u16*   QKV   = (u16*)(ws + 25182208);          // 48 MB (8192 x [Q|K|V])
  float* Gpart = (float*)(ws + 75513856);        //  8 MB
  float* qpart = (float*)(ws + 83902464);        // 128 KB   -> end ~80 MB

  k_prep<<<8192, 256, 0, stream>>>(X, Wq, Wk, Wv, Wo, bq, bk, bv, Xb, Wqkvt, Wot, bias3);
  k_gemm_bt<u16><<<dim3(24, 64), 256, 0, stream>>>(Xb, Wqkvt, bias3, QKV, 8192, 3072, 1024);
  k_gpart2<<<dim3(8, 64), 256, 0, stream>>>(QKV, Gpart, qpart);
  k_kgd<<<dim3(8, 64), 256, 0, stream>>>(QKV, Gpart, qpart, mid);
  k_gemm_bt<float><<<dim3(8, 64), 256, 0, stream>>>(mid, Wot, bo, out, 8192, 1024, 1024);
}

// Round 6
// 257.383 us; speedup vs baseline: 1.0246x; 1.0246x over previous
//
#include <hip/hip_runtime.h>
#include <type_traits>

typedef unsigned short u16;
typedef __attribute__((ext_vector_type(8))) short short8;   // 8 bf16 (4 VGPRs) MFMA frag
typedef __attribute__((ext_vector_type(4))) float floatx4;  // MFMA acc

#define DEV __device__ __forceinline__

DEV float bf2f(u16 u) { return __uint_as_float(((unsigned)u) << 16); }
DEV u16 f2bf(float f) {                       // RNE fp32->bf16
  unsigned u = __float_as_uint(f);
  u += 0x7fffu + ((u >> 16) & 1u);
  return (u16)(u >> 16);
}
DEV void unpack8(uint4 v, float* f) {
  f[0] = __uint_as_float(v.x << 16); f[1] = __uint_as_float(v.x & 0xffff0000u);
  f[2] = __uint_as_float(v.y << 16); f[3] = __uint_as_float(v.y & 0xffff0000u);
  f[4] = __uint_as_float(v.z << 16); f[5] = __uint_as_float(v.z & 0xffff0000u);
  f[6] = __uint_as_float(v.w << 16); f[7] = __uint_as_float(v.w & 0xffff0000u);
}
DEV void async16(const void* g, void* lds) {  // 16B global->LDS DMA (lane*16 implicit)
  __builtin_amdgcn_global_load_lds((const __attribute__((address_space(1))) void*)g,
                                   (__attribute__((address_space(3))) void*)lds, 16, 0, 0);
}

// ---------------- fused prep: X fp32->bf16 convert (blocks 0..4095) +
//                  weight transpose-convert + bias3 pack (blocks 4096..8191) ----------------
__global__ __launch_bounds__(256)
void k_prep(const float* __restrict__ X, const float* __restrict__ Wq, const float* __restrict__ Wk,
            const float* __restrict__ Wv, const float* __restrict__ Wo,
            const float* __restrict__ bq, const float* __restrict__ bk, const float* __restrict__ bv,
            u16* __restrict__ Xb, u16* __restrict__ Wqkvt, u16* __restrict__ Wot,
            float* __restrict__ bias3) {
  if (blockIdx.x < 4096) {                  // ---- X convert ----
    size_t i = ((size_t)blockIdx.x * 256 + threadIdx.x) * 8;
    float4 a = *(const float4*)(X + i);
    float4 b = *(const float4*)(X + i + 4);
    union { u16 s[8]; uint4 v; } o;
    o.s[0]=f2bf(a.x); o.s[1]=f2bf(a.y); o.s[2]=f2bf(a.z); o.s[3]=f2bf(a.w);
    o.s[4]=f2bf(b.x); o.s[5]=f2bf(b.y); o.s[6]=f2bf(b.z); o.s[7]=f2bf(b.w);
    *(uint4*)(Xb + i) = o.v;
    return;
  }
  // ---- weight transpose-convert: rb = z*1024 + by*32 + bx ----
  const int rb = blockIdx.x - 4096;
  const int z = rb >> 10, bxx = rb & 31, byy = (rb >> 5) & 31;
  const float* src; u16* dst;
  switch (z) {
    case 0:  src = Wq; dst = Wqkvt;            break;
    case 1:  src = Wk; dst = Wqkvt + 1048576;  break;
    case 2:  src = Wv; dst = Wqkvt + 2097152;  break;
    default: src = Wo; dst = Wot;              break;
  }
  __shared__ float tile[32][33];
  int tx = threadIdx.x & 31, ty = threadIdx.x >> 5;  // 32 x 8
  int n0 = bxx * 32, k0 = byy * 32;
  #pragma unroll
  for (int i = 0; i < 32; i += 8) tile[ty + i][tx] = src[(size_t)(k0 + ty + i) * 1024 + n0 + tx];
  if (z == 3 && bxx == 0 && byy == 0) {
    for (int i = threadIdx.x; i < 3072; i += 256)
      bias3[i] = (i < 1024) ? bq[i] : (i < 2048 ? bk[i - 1024] : bv[i - 2048]);
  }
  __syncthreads();
  #pragma unroll
  for (int i = 0; i < 32; i += 8) dst[(size_t)(n0 + ty + i) * 1024 + k0 + tx] = f2bf(tile[tx][ty + i]);
}

// ---------------- bf16 MFMA GEMM: C[M,N] = A[M,K] * Bt[N,K]^T + bias ----------------
// m97 structure + BK=64 as TWO packed 32-k half-tiles: halves the barrier count while
// keeping the exact lane-contiguous global_load_lds staging and the conflict-free
// 64-B-row-stride ds_read_b128 pattern of BK=32. LDS 32 KB -> occupancy still VGPR-bound.
template <typename OutT>
__global__ __launch_bounds__(256)
void k_gemm_bt(const u16* __restrict__ A, const u16* __restrict__ B,
               const float* __restrict__ bias, OutT* __restrict__ C,
               int M, int N, int K) {
  __shared__ __align__(16) u16 As[2 * 128 * 32];   // [half][row][32k]
  __shared__ __align__(16) u16 Bs[2 * 128 * 32];
  const int t = threadIdx.x;
  const int w = t >> 6, lane = t & 63;
  const int m0 = blockIdx.y << 7, n0 = blockIdx.x << 7;
  const int wr = (w >> 1) << 6, wc = (w & 1) << 6;

  floatx4 acc[4][4];
  #pragma unroll
  for (int i = 0; i < 4; ++i)
    #pragma unroll
    for (int j = 0; j < 4; ++j)
      #pragma unroll
      for (int k = 0; k < 4; ++k) acc[i][j][k] = 0.f;

  const int rowA0 = t >> 2, koff = (t & 3) << 3;      // round 0: idx = t
  const int rowA1 = (256 + t) >> 2;                   // round 1: idx = 256+t (same koff)
  const int lr = lane & 15, lko = (lane >> 4) << 3;

  const size_t offA0 = (size_t)(m0 + rowA0) * K + koff;
  const size_t offA1 = (size_t)(m0 + rowA1) * K + koff;
  const size_t offB0 = (size_t)(n0 + rowA0) * K + koff;
  const size_t offB1 = (size_t)(n0 + rowA1) * K + koff;

  for (int kt = 0; kt < K; kt += 64) {
    __syncthreads();
    // half 0 (k = kt..kt+31)
    async16(A + offA0 + kt, &As[(w << 6) * 8]);
    async16(B + offB0 + kt, &Bs[(w << 6) * 8]);
    async16(A + offA1 + kt, &As[(256 + (w << 6)) * 8]);
    async16(B + offB1 + kt, &Bs[(256 + (w << 6)) * 8]);
    // half 1 (k = kt+32..kt+63), packed at element offset 4096
    async16(A + offA0 + kt + 32, &As[4096 + (w << 6) * 8]);
    async16(B + offB0 + kt + 32, &Bs[4096 + (w << 6) * 8]);
    async16(A + offA1 + kt + 32, &As[4096 + (256 + (w << 6)) * 8]);
    async16(B + offB1 + kt + 32, &Bs[4096 + (256 + (w << 6)) * 8]);
    __syncthreads();
    #pragma unroll
    for (int hf = 0; hf < 2; ++hf) {
      const int hb = hf << 12;             // 0 or 4096 elements
      short8 af[4], bfr[4];
      #pragma unroll
      for (int i = 0; i < 4; ++i) af[i]  = *(const short8*)&As[hb + (wr + (i << 4) + lr) * 32 + lko];
      #pragma unroll
      for (int j = 0; j < 4; ++j) bfr[j] = *(const short8*)&Bs[hb + (wc + (j << 4) + lr) * 32 + lko];
      #pragma unroll
      for (int i = 0; i < 4; ++i)
        #pragma unroll
        for (int j = 0; j < 4; ++j)
          acc[i][j] = __builtin_amdgcn_mfma_f32_16x16x32_bf16(af[i], bfr[j], acc[i][j], 0, 0, 0);
    }
  }
  // C/D layout: col = lane&15, row = (lane>>4)*4 + reg
  const int lq = (lane >> 4) << 2;
  #pragma unroll
  for (int j = 0; j < 4; ++j) {
    const int cn = n0 + wc + (j << 4) + lr;
    const float bv = bias[cn];
    #pragma unroll
    for (int i = 0; i < 4; ++i) {
      const int rm = m0 + wr + (i << 4) + lq;
      #pragma unroll
      for (int rr = 0; rr < 4; ++rr) {
        float v = acc[i][j][rr] + bv;
        if constexpr (std::is_same<OutT, u16>::value) C[(size_t)(rm + rr) * N + cn] = f2bf(v);
        else                                          C[(size_t)(rm + rr) * N + cn] = v;
      }
    }
  }
}

// ---------------- Gram partials via MFMA + qsum partials ----------------
// Per block (chunk, nh): Qt = Q^T slab (64 x, 256 a) in LDS; one b128 frag set serves as
// both A and B operand (Gram symmetry); wave w computes C tile-row i=w.
__global__ __launch_bounds__(256)
void k_gpart2(const u16* __restrict__ QKV, float* __restrict__ Gpart, float* __restrict__ qpart) {
  const int chunk = blockIdx.x;            // 0..7 (256 a each)
  const int nh = blockIdx.y;               // 0..63
  const int n = nh >> 4, h = nh & 15;
  const int t = threadIdx.x, w = t >> 6, lane = t & 63;
  const int lr = lane & 15, lko = (lane >> 4) << 3;

  __shared__ __align__(16) u16 Qt[64 * 264];   // x-major, a-stride-padded (33.8 KB)
  __shared__ float red[256];

  // transpose-in: thread t <-> a_local = t; reads its full 64-dim Q row (8x uint4, 128 B)
  const int a = chunk * 256 + t;
  const uint4* qp = (const uint4*)(QKV + (size_t)(n * 2048 + h * 128 + (a >> 4)) * 3072 + ((t & 15) << 6));
  union { u16 s[8]; uint4 v; } qv[8];
  #pragma unroll
  for (int j = 0; j < 8; ++j) qv[j].v = qp[j];
  #pragma unroll
  for (int j = 0; j < 8; ++j)
    #pragma unroll
    for (int e = 0; e < 8; ++e)
      Qt[(j * 8 + e) * 264 + t] = qv[j].s[e];   // writes: consecutive a per lane -> 2-way, free
  __syncthreads();

  // qsum partial: thread (x = t&63, c = t>>6) sums Qt[x][c*64 .. +63]
  {
    const int x = t & 63, c = t >> 6;
    const u16* base = &Qt[x * 264 + c * 64];
    float s = 0.f;
    #pragma unroll
    for (int k = 0; k < 8; ++k) {
      float f[8]; unpack8(*(const uint4*)(base + k * 8), f);
      #pragma unroll
      for (int e = 0; e < 8; ++e) s += f[e];
    }
    red[t] = s;
  }
  __syncthreads();
  if (t < 64)
    qpart[((size_t)nh * 8 + chunk) * 64 + t] = red[t] + red[t + 64] + red[t + 128] + red[t + 192];

  // Gram: K-loop over 256 a in 8 steps of 32; wave w owns C tile-row i=w
  floatx4 acc[4];
  #pragma unroll
  for (int j = 0; j < 4; ++j)
    #pragma unroll
    for (int k = 0; k < 4; ++k) acc[j][k] = 0.f;
  for (int ks = 0; ks < 8; ++ks) {
    short8 f[4];
    #pragma unroll
    for (int i = 0; i < 4; ++i) f[i] = *(const short8*)&Qt[((i << 4) + lr) * 264 + (ks << 5) + lko];
    #pragma unroll
    for (int j = 0; j < 4; ++j)
      acc[j] = __builtin_amdgcn_mfma_f32_16x16x32_bf16(f[w], f[j], acc[j], 0, 0, 0);
  }
  float* o = Gpart + ((size_t)nh * 8 + chunk) * 4096;
  const int quad = lane >> 4;
  #pragma unroll
  for (int j = 0; j < 4; ++j)
    #pragma unroll
    for (int r = 0; r < 4; ++r)
      o[((w << 4) + (quad << 2) + r) * 64 + (j << 4) + lr] = acc[j][r];
}

// ---------------- fused: G-reduce -> U = K*G (MFMA, LDS) -> Taylor denom/diag -> mid = diag*V ----
__global__ __launch_bounds__(256)
void k_kgd(const u16* __restrict__ QKV, const float* __restrict__ Gpart,
           const float* __restrict__ qpart, u16* __restrict__ mid) {
  const int chunk = blockIdx.x;            // 0..7 (256 a each)
  const int nh = blockIdx.y;               // 0..63
  const int n = nh >> 4, h = nh & 15;
  const int t = threadIdx.x, w = t >> 6, lane = t & 63;
  const int lr = lane & 15, lko = (lane >> 4) << 3;

  __shared__ u16 Gs[4096];                 // bf16 G_h, 64x64 (8 KB)
  __shared__ __align__(16) u16 Us[256 * 72];  // bf16 U rows, padded stride 72 (36.9 KB)
  __shared__ float qs[64];

  // --- stage 0: reduce Gpart (8 chunks) -> Gs bf16; load qs ---
  const float* gp0 = Gpart + (size_t)nh * 8 * 4096;
  #pragma unroll
  for (int i = 0; i < 16; ++i) {
    int e = (i << 8) + t;
    float s = 0.f;
    #pragma unroll
    for (int c = 0; c < 8; ++c) s += gp0[c * 4096 + e];
    Gs[e] = f2bf(s);
  }
  if (t < 64) {
    float s = 0.f;
    #pragma unroll
    for (int rc = 0; rc < 8; ++rc) s += qpart[((size_t)nh * 8 + rc) * 64 + t];
    qs[t] = s;
  }
  __syncthreads();

  // --- stage 1: U = K * G via MFMA (each wave: 64 a-rows x 64 cols) ---
  short8 af[4][2], bfr[4][2];
  #pragma unroll
  for (int i = 0; i < 4; ++i) {
    const int arow = chunk * 16 + (w << 2) + i;         // (a>>4) within head
    const u16* kp = QKV + (size_t)(n * 2048 + h * 128 + arow) * 3072 + 1024 + lr * 64;
    #pragma unroll
    for (int s = 0; s < 2; ++s) af[i][s] = *(const short8*)(kp + s * 32 + lko);
  }
  #pragma unroll
  for (int j = 0; j < 4; ++j)
    #pragma unroll
    for (int s = 0; s < 2; ++s)
      bfr[j][s] = *(const short8*)&Gs[((j << 4) + lr) * 64 + s * 32 + lko];
  floatx4 acc[4][4];
  #pragma unroll
  for (int i = 0; i < 4; ++i)
    #pragma unroll
    for (int j = 0; j < 4; ++j)
      #pragma unroll
      for (int k = 0; k < 4; ++k) acc[i][j][k] = 0.f;
  #pragma unroll
  for (int s = 0; s < 2; ++s)
    #pragma unroll
    for (int i = 0; i < 4; ++i)
      #pragma unroll
      for (int j = 0; j < 4; ++j)
        acc[i][j] = __builtin_amdgcn_mfma_f32_16x16x32_bf16(af[i][s], bfr[j][s], acc[i][j], 0, 0, 0);
  const int rq = (lane >> 4) << 2;
  #pragma unroll
  for (int i = 0; i < 4; ++i)
    #pragma unroll
    for (int j = 0; j < 4; ++j)
      #pragma unroll
      for (int r = 0; r < 4; ++r) {
        int a_local = (w << 6) + (i << 4) + rq + r;     // 0..255
        Us[a_local * 72 + (j << 4) + lr] = f2bf(acc[i][j][r]);
      }
  __syncthreads();

  // --- stage 2: per-thread a: Taylor denom + diag; mid = diag * V ---
  const int b = chunk * 256 + t;           // a within head
  const int R = n * 2048 + h * 128 + (b >> 4);
  const u16* row = QKV + (size_t)R * 3072 + ((b & 15) << 6);
  const uint4* qp = (const uint4*)row;
  const uint4* kp = (const uint4*)(row + 1024);
  const uint4* vp = (const uint4*)(row + 2048);
  const uint4* up = (const uint4*)&Us[t * 72];
  float sbb = 0.f, s1 = 0.f, quad = 0.f;
  #pragma unroll
  for (int xo = 0; xo < 8; ++xo) {
    float kx[8], qx[8], ux[8];
    unpack8(kp[xo], kx); unpack8(qp[xo], qx); unpack8(up[xo], ux);
    #pragma unroll
    for (int xi = 0; xi < 8; ++xi) {
      sbb  += qx[xi] * kx[xi];
      quad += ux[xi] * kx[xi];
      s1   += qs[xo * 8 + xi] * kx[xi];
    }
  }
  const float c1 = 0.0009765625f;  // 1/1024
  float denom = 2048.f + s1 * c1 + 0.5f * quad * c1 * c1;
  float d = expf(sbb * c1) / denom;
  u16* mp = mid + (size_t)R * 1024 + ((b & 15) << 6);
  #pragma unroll
  for (int xo = 0; xo < 8; ++xo) {
    float f[8]; unpack8(vp[xo], f);
    union { u16 s[8]; uint4 v; } o;
    #pragma unroll
    for (int k = 0; k < 8; ++k) o.s[k] = f2bf(f[k] * d);
    *(uint4*)(mp + xo * 8) = o.v;
  }
}

// ---------------- launch ----------------
extern "C" void kernel_launch(void* const* d_in, const int* in_sizes, int n_in,
                              void* d_out, int out_size, void* d_ws, size_t ws_size,
                              hipStream_t stream) {
  (void)in_sizes; (void)n_in; (void)out_size; (void)ws_size;
  const float* X  = (const float*)d_in[0];
  const float* Wq = (const float*)d_in[1];
  const float* bq = (const float*)d_in[2];
  const float* Wk = (const float*)d_in[3];
  const float* bk = (const float*)d_in[4];
  const float* Wv = (const float*)d_in[5];
  const float* bv = (const float*)d_in[6];
  const float* Wo = (const float*)d_in[7];
  const float* bo = (const float*)d_in[8];
  float* out = (float*)d_out;
  char* ws = (char*)d_ws;

  u16*   Xb    = (u16*)(ws + 0);                 // 16 MB (dead after QKV GEMM)
  u16*   mid   = (u16*)(ws + 0);                 // overlays Xb (written after Xb is dead)
  u16*   Wqkvt = (u16*)(ws + 16777216);          //  6 MB
  u16*   Wot   = (u16*)(ws + 23068672);          //  2 MB
  float* bias3 = (float*)(ws + 25165824);        // 12 KB
  u16*   QKV   = (u16*)(ws + 25182208);          // 48 MB (8192 x [Q|K|V])
  float* Gpart = (float*)(ws + 75513856);        //  8 MB
  float* qpart = (float*)(ws + 83902464);        // 128 KB   -> end ~80 MB

  k_prep<<<8192, 256, 0, stream>>>(X, Wq, Wk, Wv, Wo, bq, bk, bv, Xb, Wqkvt, Wot, bias3);
  k_gemm_bt<u16><<<dim3(24, 64), 256, 0, stream>>>(Xb, Wqkvt, bias3, QKV, 8192, 3072, 1024);
  k_gpart2<<<dim3(8, 64), 256, 0, stream>>>(QKV, Gpart, qpart);
  k_kgd<<<dim3(8, 64), 256, 0, stream>>>(QKV, Gpart, qpart, mid);
  k_gemm_bt<float><<<dim3(8, 64), 256, 0, stream>>>(mid, Wot, bo, out, 8192, 1024, 1024);
}